// Round 12
// baseline (163.842 us; speedup 1.0000x reference)
//
#include <hip/hip_runtime.h>
#include <cstdint>
#include <cstddef>

#define NB 2048
#define NT 512
#define ND 64
#define NR 50
#define NKK 16
#define REVP 68          // review row stride (floats)
#define ARING 51200      // byte offset of B ring in arena (A-hi = 50*1024)

typedef __attribute__((ext_vector_type(8))) short bf16x8;
typedef __attribute__((ext_vector_type(4))) float f32x4;

__device__ inline unsigned short f2bf_rne(float x) {
    unsigned int u = __float_as_uint(x);
    u += 0x7fffu + ((u >> 16) & 1u);
    return (unsigned short)(u >> 16);
}

// 8 f32 -> 8 bf16 (RNE) via v_cvt_pk_bf16_f32
__device__ inline bf16x8 cvt8_rne(float4 v0, float4 v1) {
    union { unsigned int u[4]; bf16x8 v; } P;
    asm("v_cvt_pk_bf16_f32 %0, %1, %2" : "=v"(P.u[0]) : "v"(v0.x), "v"(v0.y));
    asm("v_cvt_pk_bf16_f32 %0, %1, %2" : "=v"(P.u[1]) : "v"(v0.z), "v"(v0.w));
    asm("v_cvt_pk_bf16_f32 %0, %1, %2" : "=v"(P.u[2]) : "v"(v1.x), "v"(v1.y));
    asm("v_cvt_pk_bf16_f32 %0, %1, %2" : "=v"(P.u[3]) : "v"(v1.z), "v"(v1.w));
    return P.v;
}

__device__ inline void gload16(const void* gsrc, void* ldst) {
    __builtin_amdgcn_global_load_lds(
        (const __attribute__((address_space(1))) unsigned int*)gsrc,
        (__attribute__((address_space(3))) unsigned int*)ldst, 16, 0, 0);
}

// ---------------------------------------------------------------------------
// Pack topic_w into main-GEMM B-frag order (single bf16, RNE) and fc weights
// into epilogue B-frag order (K=128: rows 0-63 = fc_r_w, 64-127 = fc_a_w).
__global__ __launch_bounds__(256) void prep_kernel(
    const float* __restrict__ tw,
    const float* __restrict__ fc_u_w, const float* __restrict__ fc_ru_w,
    const float* __restrict__ fc_i_w, const float* __restrict__ fc_ri_w,
    unsigned short* __restrict__ bhi,
    unsigned short* __restrict__ fuhi, unsigned short* __restrict__ fihi)
{
    int i = blockIdx.x * 256 + threadIdx.x;          // 192*256 = 49152
    if (i < 32768) {
        int j  = i & 7;
        int l  = (i >> 3) & 63;
        int n  = (i >> 9) & 3;
        int kk = i >> 11;                            // 0..15
        int t = kk * 32 + ((l >> 4) << 3) + j;
        int d = n * 16 + (l & 15);
        bhi[i] = f2bf_rne(tw[t * ND + d]);
    } else {
        int q = i - 32768;                           // 0..16383
        int br = q >> 13;                            // 0 user, 1 item
        int e = q & 8191;
        int j  = e & 7;
        int l  = (e >> 3) & 63;
        int n  = (e >> 9) & 3;
        int kk = e >> 11;                            // 0..3
        int k = kk * 32 + ((l >> 4) << 3) + j;       // 0..127
        int col = n * 16 + (l & 15);
        const float* W = (k < 64) ? (br ? fc_ri_w : fc_ru_w)
                                  : (br ? fc_i_w  : fc_u_w);
        unsigned short hi = f2bf_rne(W[(k & 63) * ND + col]);
        if (br) fihi[e] = hi; else fuhi[e] = hi;
    }
}

// ---------------------------------------------------------------------------
__global__ __launch_bounds__(256) void colsum_kernel(const float* __restrict__ tw,
                                                     float* __restrict__ colsum) {
    __shared__ float part[4][ND];
    int d = threadIdx.x & 63, p = threadIdx.x >> 6;
    float s = 0.f;
    for (int t = p; t < NT; t += 4) s += tw[t * ND + d];
    part[p][d] = s;
    __syncthreads();
    if (threadIdx.x < ND)
        colsum[d] = part[0][d] + part[1][d] + part[2][d] + part[3][d];
}

// ---------------------------------------------------------------------------
// One block per (branch, batch element), 4 waves, 2 blocks/CU.
// Phase 1: stream FULL A tile (contiguous 102.4 KB f32) -> bf16 RNE -> LDS
//          (pure copy loop: coalesced dwordx4, full unroll, XOR-swizzled store)
// Phase 2: K-loop pure LDS->MFMA; B-hi staged in 8KB eighths, ring-2,
//          counted vmcnt(2) (never 0 mid-ring).
__global__ __launch_bounds__(256, 2) void branch_kernel(
    const int* __restrict__ user, const int* __restrict__ item,
    const float* __restrict__ user_r_topic, const float* __restrict__ item_r_topic,
    const float* __restrict__ user_embed_w, const float* __restrict__ item_embed_w,
    const float* __restrict__ user_att_w, const float* __restrict__ item_att_w,
    const unsigned short* __restrict__ bhi,
    const unsigned short* __restrict__ fuhi, const unsigned short* __restrict__ fihi,
    const float* __restrict__ fc_u_b, const float* __restrict__ fc_ru_b,
    const float* __restrict__ fc_i_b, const float* __restrict__ fc_ri_b,
    const float* __restrict__ h_u_w, const float* __restrict__ h_u_b,
    const float* __restrict__ h_i_w, const float* __restrict__ h_i_b,
    const float* __restrict__ colsum,
    float* __restrict__ u_vec, float* __restrict__ i_vec)
{
    // arena: A-hi bf16 [50][512] XOR-swizzled rows at [0, 51200)
    //        B ring-2 of 8KB eighths at [51200, 67584)
    // rev[50][68] f32 overlays [0, 13600) after the K-loop.
    __shared__ __align__(16) unsigned char arena[ARING + 16384];
    __shared__ float lds_logit[NR + 2];

    const int tid = threadIdx.x, wave = tid >> 6, lane = tid & 63;
    const int g = lane >> 4, c16 = lane & 15;

    const int bb = blockIdx.x;
    const int branch = bb >> 11;          // 0 = user, 1 = item
    const int b = bb & (NB - 1);

    const int*   ids     = branch ? item           : user;
    const float* r_topic = branch ? item_r_topic   : user_r_topic;
    const float* emb_w   = branch ? item_embed_w   : user_embed_w;
    const float* att_w   = branch ? item_att_w     : user_att_w;
    const unsigned short* fhi = branch ? fihi : fuhi;
    const float* fc_a_b  = branch ? fc_i_b         : fc_u_b;
    const float* fc_r_b  = branch ? fc_ri_b        : fc_ru_b;
    const float* h_w     = branch ? h_i_w          : h_u_w;
    const float* h_b     = branch ? h_i_b          : h_u_b;
    float*       out_vec = branch ? i_vec          : u_vec;

    const int id = ids[b];
    const int rowm = wave * 16 + c16;
    const int rowc = rowm < NR ? rowm : NR - 1;

    // ---- Phase 1: stream A (contiguous 25600 f32) -> bf16 -> LDS ----
    const float* Abase = r_topic + (size_t)b * NR * NT;
#pragma unroll
    for (int i = 0; i < 13; ++i) {
        int gi = i * 256 + tid;                      // granule = 8 f32 = 32 B
        if (gi < 3200) {
            float4 v0 = *reinterpret_cast<const float4*>(Abase + gi * 8);
            float4 v1 = *reinterpret_cast<const float4*>(Abase + gi * 8 + 4);
            bf16x8 hv = cvt8_rne(v0, v1);
            int row = gi >> 6, c8 = gi & 63;         // 64 slots/row
            *reinterpret_cast<bf16x8*>(arena + row * 1024 + ((c8 ^ (row & 7)) << 4)) = hv;
        }
    }
    __syncthreads();                                 // A resident (full drain)

    // ---- Phase 2: K-loop, B eighth-ring ----
    auto stageB8 = [&](int j, int slot) {            // eighth j -> ring slot
        const unsigned char* src = (const unsigned char*)bhi + (size_t)j * 8192
                                   + wave * 2048 + (size_t)lane * 16;
        unsigned char* dst = arena + ARING + slot * 8192 + wave * 2048;
        gload16(src, dst);
        gload16(src + 1024, dst + 1024);
    };

    f32x4 acc[4];
#pragma unroll
    for (int n = 0; n < 4; ++n) acc[n] = (f32x4){0.f, 0.f, 0.f, 0.f};

    auto kstep = [&](int kk, const unsigned char* bring) {
        bf16x8 af = *reinterpret_cast<const bf16x8*>(
            arena + rowc * 1024 + (((kk * 4 + g) ^ (rowc & 7)) << 4));
        const unsigned char* bp = bring + (kk & 1) * 4096 + (size_t)lane * 16;
#pragma unroll
        for (int n = 0; n < 4; ++n) {
            bf16x8 bh = *reinterpret_cast<const bf16x8*>(bp + n * 1024);
            acc[n] = __builtin_amdgcn_mfma_f32_16x16x32_bf16(af, bh, acc[n], 0, 0, 0);
        }
    };

    stageB8(0, 0);
    stageB8(1, 1);
    asm volatile("s_waitcnt vmcnt(2)" ::: "memory"); // eighth 0 landed (1 in flight)
    __builtin_amdgcn_sched_barrier(0);
    __builtin_amdgcn_s_barrier();
    __builtin_amdgcn_sched_barrier(0);

#pragma unroll
    for (int j = 0; j < 8; ++j) {
        const unsigned char* bring = arena + ARING + (j & 1) * 8192;
        kstep(2 * j,     bring);
        kstep(2 * j + 1, bring);
        if (j < 7) {
            __builtin_amdgcn_sched_barrier(0);
            __builtin_amdgcn_s_barrier();            // all done reading ring[j&1]
            __builtin_amdgcn_sched_barrier(0);
            if (j < 6) {
                stageB8(j + 2, j & 1);
                asm volatile("s_waitcnt vmcnt(2)" ::: "memory");  // e(j+1) landed
            } else {
                asm volatile("s_waitcnt vmcnt(0)" ::: "memory");  // e7 landed
            }
            __builtin_amdgcn_sched_barrier(0);
            __builtin_amdgcn_s_barrier();            // e(j+1) visible block-wide
            __builtin_amdgcn_sched_barrier(0);
        }
    }

    __syncthreads();                                 // all LDS reads done -> overlay
    float (*rev)[REVP] = reinterpret_cast<float(*)[REVP]>(arena);
#pragma unroll
    for (int n = 0; n < 4; ++n)
#pragma unroll
        for (int r4 = 0; r4 < 4; ++r4) {
            int r = wave * 16 + g * 4 + r4;
            if (r < NR) rev[r][n * 16 + c16] = acc[n][r4];
        }
    // no barrier: epilogue reads only this wave's own rows

    // ---- epilogue s-matmul: s[50x64] = review@fcR + att@fcA (K=128, bf16) ----
    f32x4 s4[4];
#pragma unroll
    for (int n = 0; n < 4; ++n) s4[n] = (f32x4){0.f, 0.f, 0.f, 0.f};

#pragma unroll
    for (int kk2 = 0; kk2 < 4; ++kk2) {
        bf16x8 bh[4];
#pragma unroll
        for (int n = 0; n < 4; ++n)
            bh[n] = *(reinterpret_cast<const bf16x8*>(fhi + (size_t)(kk2 * 4 + n) * 512) + lane);
        bf16x8 ah;
        if (kk2 < 2) {
            const float* rp = &rev[rowc][kk2 * 32 + g * 8];
            ah = cvt8_rne(*reinterpret_cast<const float4*>(rp),
                          *reinterpret_cast<const float4*>(rp + 4));
        } else {
            const float* ap = att_w + (size_t)id * ND + (kk2 - 2) * 32 + g * 8;
            ah = cvt8_rne(*reinterpret_cast<const float4*>(ap),
                          *reinterpret_cast<const float4*>(ap + 4));
        }
#pragma unroll
        for (int n = 0; n < 4; ++n)
            s4[n] = __builtin_amdgcn_mfma_f32_16x16x32_bf16(ah, bh[n], s4[n], 0, 0, 0);
    }

    // bias + relu + dot with h_w, then 16-lane reduce -> logits
    const float hb = h_b[0];
    float p0 = 0.f, p1 = 0.f, p2 = 0.f, p3 = 0.f;
#pragma unroll
    for (int n = 0; n < 4; ++n) {
        float hwn = h_w[n * 16 + c16];
        float bs = fc_r_b[n * 16 + c16] + fc_a_b[n * 16 + c16];
        p0 = fmaf(fmaxf(s4[n][0] + bs, 0.f), hwn, p0);
        p1 = fmaf(fmaxf(s4[n][1] + bs, 0.f), hwn, p1);
        p2 = fmaf(fmaxf(s4[n][2] + bs, 0.f), hwn, p2);
        p3 = fmaf(fmaxf(s4[n][3] + bs, 0.f), hwn, p3);
    }
#pragma unroll
    for (int off = 1; off < 16; off <<= 1) {
        p0 += __shfl_xor(p0, off);
        p1 += __shfl_xor(p1, off);
        p2 += __shfl_xor(p2, off);
        p3 += __shfl_xor(p3, off);
    }
    if (c16 == 0) {
        int rb = wave * 16 + g * 4;
        if (rb + 0 < NR) lds_logit[rb + 0] = p0 + hb;
        if (rb + 1 < NR) lds_logit[rb + 1] = p1 + hb;
        if (rb + 2 < NR) lds_logit[rb + 2] = p2 + hb;
        if (rb + 3 < NR) lds_logit[rb + 3] = p3 + hb;
    }
    __syncthreads();   // publish rev rows + logits to wave 0

    // softmax + pooling + colsum scale + emb add (wave 0)
    if (wave == 0) {
        float m = -1e30f;
        for (int r = 0; r < NR; ++r) m = fmaxf(m, lds_logit[r]);
        float sum = 0.f;
        for (int r = 0; r < NR; ++r) sum += __expf(lds_logit[r] - m);
        float inv = 1.f / sum;
        float feat = 0.f;
        for (int r = 0; r < NR; ++r)
            feat = fmaf(__expf(lds_logit[r] - m), rev[r][lane], feat);
        feat *= inv;
        out_vec[(size_t)b * ND + lane] = feat * colsum[lane] + emb_w[(size_t)id * ND + lane];
    }
}

// ---------------------------------------------------------------------------
__global__ __launch_bounds__(64) void final_kernel(
    const float* __restrict__ u_vec, const float* __restrict__ i_vec,
    const float* __restrict__ fc_pre_w, const float* __restrict__ fc_pre_b,
    float* __restrict__ out)
{
    int b = blockIdx.x, lane = threadIdx.x;
    float v = u_vec[(size_t)b * ND + lane] * fc_pre_w[lane]
            + i_vec[(size_t)b * ND + lane] * fc_pre_w[ND + lane];
#pragma unroll
    for (int off = 32; off; off >>= 1) v += __shfl_xor(v, off);
    if (lane == 0) out[b] = fmaxf(v + fc_pre_b[0], 0.f);
}

// ---------------------------------------------------------------------------
extern "C" void kernel_launch(void* const* d_in, const int* in_sizes, int n_in,
                              void* d_out, int out_size, void* d_ws, size_t ws_size,
                              hipStream_t stream) {
    (void)in_sizes; (void)n_in; (void)out_size; (void)ws_size;

    const int*   user         = (const int*)d_in[0];
    const int*   item         = (const int*)d_in[1];
    const float* user_r_topic = (const float*)d_in[2];
    const float* item_r_topic = (const float*)d_in[3];
    const float* user_embed_w = (const float*)d_in[4];
    const float* item_embed_w = (const float*)d_in[5];
    const float* user_att_w   = (const float*)d_in[6];
    const float* item_att_w   = (const float*)d_in[7];
    const float* topic_w      = (const float*)d_in[8];
    const float* fc_u_w       = (const float*)d_in[9];
    const float* fc_u_b       = (const float*)d_in[10];
    const float* fc_ru_w      = (const float*)d_in[11];
    const float* fc_ru_b      = (const float*)d_in[12];
    const float* fc_i_w       = (const float*)d_in[13];
    const float* fc_i_b       = (const float*)d_in[14];
    const float* fc_ri_w      = (const float*)d_in[15];
    const float* fc_ri_b      = (const float*)d_in[16];
    const float* h_u_w        = (const float*)d_in[17];
    const float* h_u_b        = (const float*)d_in[18];
    const float* h_i_w        = (const float*)d_in[19];
    const float* h_i_b        = (const float*)d_in[20];
    const float* fc_pre_w     = (const float*)d_in[21];
    const float* fc_pre_b     = (const float*)d_in[22];

    // workspace layout
    unsigned short* bhi  = (unsigned short*)d_ws;      // 32768
    unsigned short* fuhi = bhi + 32768;                // 8192
    unsigned short* fihi = fuhi + 8192;                // 8192
    float* colsum = (float*)(fihi + 8192);             // 64
    float* u_vec  = colsum + 64;                       // NB*ND
    float* i_vec  = u_vec + NB * ND;                   // NB*ND

    prep_kernel<<<192, 256, 0, stream>>>(topic_w, fc_u_w, fc_ru_w, fc_i_w, fc_ri_w,
                                         bhi, fuhi, fihi);
    colsum_kernel<<<1, 256, 0, stream>>>(topic_w, colsum);

    branch_kernel<<<2 * NB, 256, 0, stream>>>(
        user, item, user_r_topic, item_r_topic,
        user_embed_w, item_embed_w, user_att_w, item_att_w,
        bhi, fuhi, fihi,
        fc_u_b, fc_ru_b, fc_i_b, fc_ri_b,
        h_u_w, h_u_b, h_i_w, h_i_b,
        colsum, u_vec, i_vec);

    final_kernel<<<NB, 64, 0, stream>>>(u_vec, i_vec, fc_pre_w, fc_pre_b,
                                        (float*)d_out);
}

// Round 13
// 153.793 us; speedup vs baseline: 1.0653x; 1.0653x over previous
//
#include <hip/hip_runtime.h>
#include <cstdint>
#include <cstddef>

#define NB 2048
#define NT 512
#define ND 64
#define NR 50
#define REVP 68          // review row stride (floats)

typedef __attribute__((ext_vector_type(8))) short bf16x8;
typedef __attribute__((ext_vector_type(4))) float f32x4;

__device__ inline unsigned short f2bf_rne(float x) {
    unsigned int u = __float_as_uint(x);
    u += 0x7fffu + ((u >> 16) & 1u);
    return (unsigned short)(u >> 16);
}

// 8 f32 -> 8 bf16 (RNE) via v_cvt_pk_bf16_f32
__device__ inline bf16x8 cvt8_rne(float4 v0, float4 v1) {
    union { unsigned int u[4]; bf16x8 v; } P;
    asm("v_cvt_pk_bf16_f32 %0, %1, %2" : "=v"(P.u[0]) : "v"(v0.x), "v"(v0.y));
    asm("v_cvt_pk_bf16_f32 %0, %1, %2" : "=v"(P.u[1]) : "v"(v0.z), "v"(v0.w));
    asm("v_cvt_pk_bf16_f32 %0, %1, %2" : "=v"(P.u[2]) : "v"(v1.x), "v"(v1.y));
    asm("v_cvt_pk_bf16_f32 %0, %1, %2" : "=v"(P.u[3]) : "v"(v1.z), "v"(v1.w));
    return P.v;
}

__device__ inline void gload16(const void* gsrc, void* ldst) {
    __builtin_amdgcn_global_load_lds(
        (const __attribute__((address_space(1))) unsigned int*)gsrc,
        (__attribute__((address_space(3))) unsigned int*)ldst, 16, 0, 0);
}

// ---------------------------------------------------------------------------
// Pack topic_w into main-GEMM B-frag order (single bf16, RNE) and fc weights
// into epilogue B-frag order (K=128: rows 0-63 = fc_r_w, 64-127 = fc_a_w).
__global__ __launch_bounds__(256) void prep_kernel(
    const float* __restrict__ tw,
    const float* __restrict__ fc_u_w, const float* __restrict__ fc_ru_w,
    const float* __restrict__ fc_i_w, const float* __restrict__ fc_ri_w,
    unsigned short* __restrict__ bhi,
    unsigned short* __restrict__ fuhi, unsigned short* __restrict__ fihi)
{
    int i = blockIdx.x * 256 + threadIdx.x;          // 192*256 = 49152
    if (i < 32768) {
        int j  = i & 7;
        int l  = (i >> 3) & 63;
        int n  = (i >> 9) & 3;
        int kk = i >> 11;                            // 0..15
        int t = kk * 32 + ((l >> 4) << 3) + j;
        int d = n * 16 + (l & 15);
        bhi[i] = f2bf_rne(tw[t * ND + d]);
    } else {
        int q = i - 32768;                           // 0..16383
        int br = q >> 13;                            // 0 user, 1 item
        int e = q & 8191;
        int j  = e & 7;
        int l  = (e >> 3) & 63;
        int n  = (e >> 9) & 3;
        int kk = e >> 11;                            // 0..3
        int k = kk * 32 + ((l >> 4) << 3) + j;       // 0..127
        int col = n * 16 + (l & 15);
        const float* W = (k < 64) ? (br ? fc_ri_w : fc_ru_w)
                                  : (br ? fc_i_w  : fc_u_w);
        unsigned short hi = f2bf_rne(W[(k & 63) * ND + col]);
        if (br) fihi[e] = hi; else fuhi[e] = hi;
    }
}

// ---------------------------------------------------------------------------
__global__ __launch_bounds__(256) void colsum_kernel(const float* __restrict__ tw,
                                                     float* __restrict__ colsum) {
    __shared__ float part[4][ND];
    int d = threadIdx.x & 63, p = threadIdx.x >> 6;
    float s = 0.f;
    for (int t = p; t < NT; t += 4) s += tw[t * ND + d];
    part[p][d] = s;
    __syncthreads();
    if (threadIdx.x < ND)
        colsum[d] = part[0][d] + part[1][d] + part[2][d] + part[3][d];
}

// ---------------------------------------------------------------------------
// One block per (branch, batch element), 4 waves, 3 blocks/CU.
// B in LDS per K-half (32 KB), staged with global_load_lds; only 3 barriers
// in the whole main loop. Between barriers: ZERO barriers, ZERO LDS writes --
// each wave free-runs 8 K-steps with a PURE-HBM vmem queue (A-loads only),
// 2-step wait granularity (4 KB in flight per wait).
__global__ __launch_bounds__(256, 3) void branch_kernel(
    const int* __restrict__ user, const int* __restrict__ item,
    const float* __restrict__ user_r_topic, const float* __restrict__ item_r_topic,
    const float* __restrict__ user_embed_w, const float* __restrict__ item_embed_w,
    const float* __restrict__ user_att_w, const float* __restrict__ item_att_w,
    const unsigned short* __restrict__ bhi,
    const unsigned short* __restrict__ fuhi, const unsigned short* __restrict__ fihi,
    const float* __restrict__ fc_u_b, const float* __restrict__ fc_ru_b,
    const float* __restrict__ fc_i_b, const float* __restrict__ fc_ri_b,
    const float* __restrict__ h_u_w, const float* __restrict__ h_u_b,
    const float* __restrict__ h_i_w, const float* __restrict__ h_i_b,
    const float* __restrict__ colsum,
    float* __restrict__ u_vec, float* __restrict__ i_vec)
{
    __shared__ __align__(16) unsigned char blds[32768];   // B K-half, frag order
    __shared__ float rev[NR][REVP];                       // 13.6 KB (separate)
    __shared__ float lds_logit[NR + 2];

    const int tid = threadIdx.x, wave = tid >> 6, lane = tid & 63;
    const int g = lane >> 4, c16 = lane & 15;

    const int bb = blockIdx.x;
    const int branch = bb >> 11;          // 0 = user, 1 = item
    const int b = bb & (NB - 1);

    const int*   ids     = branch ? item           : user;
    const float* r_topic = branch ? item_r_topic   : user_r_topic;
    const float* emb_w   = branch ? item_embed_w   : user_embed_w;
    const float* att_w   = branch ? item_att_w     : user_att_w;
    const unsigned short* fhi = branch ? fihi : fuhi;
    const float* fc_a_b  = branch ? fc_i_b         : fc_u_b;
    const float* fc_r_b  = branch ? fc_ri_b        : fc_ru_b;
    const float* h_w     = branch ? h_i_w          : h_u_w;
    const float* h_b     = branch ? h_i_b          : h_u_b;
    float*       out_vec = branch ? i_vec          : u_vec;

    const int id = ids[b];
    const int rowm = wave * 16 + c16;
    const int rowc = rowm < NR ? rowm : NR - 1;   // dup-addr lanes coalesce
    const float* arow = r_topic + (size_t)b * NR * NT + (size_t)rowc * NT + g * 8;

    // stage one 32KB B-half into LDS (8 x 16B per thread, coalesced)
    auto stageB = [&](int h) {
        const unsigned char* src = (const unsigned char*)bhi + (size_t)h * 32768;
#pragma unroll
        for (int i = 0; i < 8; ++i) {
            size_t off = (size_t)(i * 256 + tid) * 16;
            gload16(src + off, blds + off);
        }
    };

    f32x4 acc[4];
#pragma unroll
    for (int n = 0; n < 4; ++n) acc[n] = (f32x4){0.f, 0.f, 0.f, 0.f};

    // two K-steps per iteration: 4 A-loads -> 1 wait -> cvt -> 8 ds_read+MFMA
    auto kstep2 = [&](int kk) {
        float4 a00 = *reinterpret_cast<const float4*>(arow + kk * 32);
        float4 a01 = *reinterpret_cast<const float4*>(arow + kk * 32 + 4);
        float4 a10 = *reinterpret_cast<const float4*>(arow + kk * 32 + 32);
        float4 a11 = *reinterpret_cast<const float4*>(arow + kk * 32 + 36);
        bf16x8 f0 = cvt8_rne(a00, a01);
        bf16x8 f1 = cvt8_rne(a10, a11);
        const int k0 = (kk & 7) * 4, k1 = ((kk + 1) & 7) * 4;
#pragma unroll
        for (int n = 0; n < 4; ++n) {
            bf16x8 b0 = *reinterpret_cast<const bf16x8*>(
                blds + (size_t)((k0 + n) * 64 + lane) * 16);
            acc[n] = __builtin_amdgcn_mfma_f32_16x16x32_bf16(f0, b0, acc[n], 0, 0, 0);
        }
#pragma unroll
        for (int n = 0; n < 4; ++n) {
            bf16x8 b1 = *reinterpret_cast<const bf16x8*>(
                blds + (size_t)((k1 + n) * 64 + lane) * 16);
            acc[n] = __builtin_amdgcn_mfma_f32_16x16x32_bf16(f1, b1, acc[n], 0, 0, 0);
        }
    };

    stageB(0);
    __syncthreads();                      // B half0 ready (compiler drains vmcnt)

#pragma unroll
    for (int kk = 0; kk < 8; kk += 2) kstep2(kk);

    __syncthreads();                      // all waves done reading half0
    stageB(1);
    __syncthreads();                      // B half1 ready

#pragma unroll
    for (int kk = 8; kk < 16; kk += 2) kstep2(kk);

    // rev: separate LDS region; wave writes/reads only its own rows
#pragma unroll
    for (int n = 0; n < 4; ++n)
#pragma unroll
        for (int r4 = 0; r4 < 4; ++r4) {
            int r = wave * 16 + g * 4 + r4;
            if (r < NR) rev[r][n * 16 + c16] = acc[n][r4];
        }

    // ---- epilogue s-matmul: s[50x64] = review@fcR + att@fcA (K=128, bf16) ----
    f32x4 s4[4];
#pragma unroll
    for (int n = 0; n < 4; ++n) s4[n] = (f32x4){0.f, 0.f, 0.f, 0.f};

#pragma unroll
    for (int kk2 = 0; kk2 < 4; ++kk2) {
        bf16x8 bh[4];
#pragma unroll
        for (int n = 0; n < 4; ++n)
            bh[n] = *(reinterpret_cast<const bf16x8*>(fhi + (size_t)(kk2 * 4 + n) * 512) + lane);
        bf16x8 ah;
        if (kk2 < 2) {
            const float* rp = &rev[rowc][kk2 * 32 + g * 8];
            ah = cvt8_rne(*reinterpret_cast<const float4*>(rp),
                          *reinterpret_cast<const float4*>(rp + 4));
        } else {
            const float* ap = att_w + (size_t)id * ND + (kk2 - 2) * 32 + g * 8;
            ah = cvt8_rne(*reinterpret_cast<const float4*>(ap),
                          *reinterpret_cast<const float4*>(ap + 4));
        }
#pragma unroll
        for (int n = 0; n < 4; ++n)
            s4[n] = __builtin_amdgcn_mfma_f32_16x16x32_bf16(ah, bh[n], s4[n], 0, 0, 0);
    }

    // bias + relu + dot with h_w, then 16-lane reduce -> logits
    const float hb = h_b[0];
    float p0 = 0.f, p1 = 0.f, p2 = 0.f, p3 = 0.f;
#pragma unroll
    for (int n = 0; n < 4; ++n) {
        float hwn = h_w[n * 16 + c16];
        float bs = fc_r_b[n * 16 + c16] + fc_a_b[n * 16 + c16];
        p0 = fmaf(fmaxf(s4[n][0] + bs, 0.f), hwn, p0);
        p1 = fmaf(fmaxf(s4[n][1] + bs, 0.f), hwn, p1);
        p2 = fmaf(fmaxf(s4[n][2] + bs, 0.f), hwn, p2);
        p3 = fmaf(fmaxf(s4[n][3] + bs, 0.f), hwn, p3);
    }
#pragma unroll
    for (int off = 1; off < 16; off <<= 1) {
        p0 += __shfl_xor(p0, off);
        p1 += __shfl_xor(p1, off);
        p2 += __shfl_xor(p2, off);
        p3 += __shfl_xor(p3, off);
    }
    if (c16 == 0) {
        int rb = wave * 16 + g * 4;
        if (rb + 0 < NR) lds_logit[rb + 0] = p0 + hb;
        if (rb + 1 < NR) lds_logit[rb + 1] = p1 + hb;
        if (rb + 2 < NR) lds_logit[rb + 2] = p2 + hb;
        if (rb + 3 < NR) lds_logit[rb + 3] = p3 + hb;
    }
    __syncthreads();   // publish rev rows + logits to wave 0

    // softmax + pooling + colsum scale + emb add (wave 0)
    if (wave == 0) {
        float m = -1e30f;
        for (int r = 0; r < NR; ++r) m = fmaxf(m, lds_logit[r]);
        float sum = 0.f;
        for (int r = 0; r < NR; ++r) sum += __expf(lds_logit[r] - m);
        float inv = 1.f / sum;
        float feat = 0.f;
        for (int r = 0; r < NR; ++r)
            feat = fmaf(__expf(lds_logit[r] - m), rev[r][lane], feat);
        feat *= inv;
        out_vec[(size_t)b * ND + lane] = feat * colsum[lane] + emb_w[(size_t)id * ND + lane];
    }
}

// ---------------------------------------------------------------------------
__global__ __launch_bounds__(64) void final_kernel(
    const float* __restrict__ u_vec, const float* __restrict__ i_vec,
    const float* __restrict__ fc_pre_w, const float* __restrict__ fc_pre_b,
    float* __restrict__ out)
{
    int b = blockIdx.x, lane = threadIdx.x;
    float v = u_vec[(size_t)b * ND + lane] * fc_pre_w[lane]
            + i_vec[(size_t)b * ND + lane] * fc_pre_w[ND + lane];
#pragma unroll
    for (int off = 32; off; off >>= 1) v += __shfl_xor(v, off);
    if (lane == 0) out[b] = fmaxf(v + fc_pre_b[0], 0.f);
}

// ---------------------------------------------------------------------------
extern "C" void kernel_launch(void* const* d_in, const int* in_sizes, int n_in,
                              void* d_out, int out_size, void* d_ws, size_t ws_size,
                              hipStream_t stream) {
    (void)in_sizes; (void)n_in; (void)out_size; (void)ws_size;

    const int*   user         = (const int*)d_in[0];
    const int*   item         = (const int*)d_in[1];
    const float* user_r_topic = (const float*)d_in[2];
    const float* item_r_topic = (const float*)d_in[3];
    const float* user_embed_w = (const float*)d_in[4];
    const float* item_embed_w = (const float*)d_in[5];
    const float* user_att_w   = (const float*)d_in[6];
    const float* item_att_w   = (const float*)d_in[7];
    const float* topic_w      = (const float*)d_in[8];
    const float* fc_u_w       = (const float*)d_in[9];
    const float* fc_u_b       = (const float*)d_in[10];
    const float* fc_ru_w      = (const float*)d_in[11];
    const float* fc_ru_b      = (const float*)d_in[12];
    const float* fc_i_w       = (const float*)d_in[13];
    const float* fc_i_b       = (const float*)d_in[14];
    const float* fc_ri_w      = (const float*)d_in[15];
    const float* fc_ri_b      = (const float*)d_in[16];
    const float* h_u_w        = (const float*)d_in[17];
    const float* h_u_b        = (const float*)d_in[18];
    const float* h_i_w        = (const float*)d_in[19];
    const float* h_i_b        = (const float*)d_in[20];
    const float* fc_pre_w     = (const float*)d_in[21];
    const float* fc_pre_b     = (const float*)d_in[22];

    // workspace layout
    unsigned short* bhi  = (unsigned short*)d_ws;      // 32768
    unsigned short* fuhi = bhi + 32768;                // 8192
    unsigned short* fihi = fuhi + 8192;                // 8192
    float* colsum = (float*)(fihi + 8192);             // 64
    float* u_vec  = colsum + 64;                       // NB*ND
    float* i_vec  = u_vec + NB * ND;                   // NB*ND

    prep_kernel<<<192, 256, 0, stream>>>(topic_w, fc_u_w, fc_ru_w, fc_i_w, fc_ri_w,
                                         bhi, fuhi, fihi);
    colsum_kernel<<<1, 256, 0, stream>>>(topic_w, colsum);

    branch_kernel<<<2 * NB, 256, 0, stream>>>(
        user, item, user_r_topic, item_r_topic,
        user_embed_w, item_embed_w, user_att_w, item_att_w,
        bhi, fuhi, fihi,
        fc_u_b, fc_ru_b, fc_i_b, fc_ri_b,
        h_u_w, h_u_b, h_i_w, h_i_b,
        colsum, u_vec, i_vec);

    final_kernel<<<NB, 64, 0, stream>>>(u_vec, i_vec, fc_pre_w, fc_pre_b,
                                        (float*)d_out);
}